// Round 5
// baseline (208.085 us; speedup 1.0000x reference)
//
#include <hip/hip_runtime.h>
#include <math.h>

// ---------------- problem constants ----------------
#define BB   16      // batch
#define TT   50      // targets per image
#define BT   (BB*TT) // 800
#define NCLS 80
#define IMGF 608.0f

#define H0 76
#define H1 38
#define H2 19
#define N0 277248   // 16*3*76*76
#define N1 69312    // 16*3*38*38
#define N2 17328    // 16*3*19*19
#define NTOT (N0+N1+N2)   // 363888

// noobj block ranges (scale-aligned so each block is single-scale; N0 == 1083*256)
#define NB0 1083
#define NB1 271
#define NB2 68
#define NBNO (NB0+NB1+NB2)                     // 1422
#define POS_BLOCKS_PER_SCALE 200               // 4 waves/block * 200 = 800 orders
#define NPOS_BLOCKS (3*POS_BLOCKS_PER_SCALE)   // 600
#define NBLK (NBNO + NPOS_BLOCKS)              // 2022

// Harness contract: d_ws is re-poisoned to 0xAA before EVERY launch, so the
// completion counter deterministically starts at 0xAAAAAAAA. Last block sees
// old == POISON + NBLK - 1 (unsigned wraparound is fine).
#define POISON_BASE 0xAAAAAAAAu

__constant__ float c_anchors[3][3][2] = {
    {{12.f,16.f},{19.f,36.f},{40.f,28.f}},
    {{36.f,75.f},{76.f,55.f},{72.f,146.f}},
    {{142.f,110.f},{192.f,243.f},{459.f,401.f}}};
__constant__ int c_H[3] = {H0, H1, H2};

__device__ __forceinline__ float sigmoidf_(float x) { return 1.0f / (1.0f + expf(-x)); }
__device__ __forceinline__ float clipf_(float x, float lo, float hi) {
    return fminf(fmaxf(x, lo), hi);
}

__device__ __forceinline__ float iou4(float ax, float ay, float aw, float ah,
                                      float bx, float by, float bw, float bh) {
    float ax1 = ax - aw * 0.5f, ay1 = ay - ah * 0.5f;
    float ax2 = ax + aw * 0.5f, ay2 = ay + ah * 0.5f;
    float bx1 = bx - bw * 0.5f, by1 = by - bh * 0.5f;
    float bx2 = bx + bw * 0.5f, by2 = by + bh * 0.5f;
    float iw = fmaxf(fminf(ax2, bx2) - fmaxf(ax1, bx1), 0.f);
    float ih = fmaxf(fminf(ay2, by2) - fmaxf(ay1, by1), 0.f);
    float inter = iw * ih;
    float uni = (ax2 - ax1) * (ay2 - ay1) + (bx2 - bx1) * (by2 - by1) - inter + 1e-7f;
    return inter / uni;
}

// anchor match + cell for one (scale, target row). returns -1 if invalid target
__device__ __forceinline__ int target_cell(const float* tr, int s, float& cx, float& cy,
                                           float& w, float& h, int& best, int& gxi, int& gyi) {
    float t4 = tr[4];
    if (!(t4 > 0.f)) return -1;
    cx = clipf_(tr[0], 0.f, 1.f);
    cy = clipf_(tr[1], 0.f, 1.f);
    w  = clipf_(tr[2], 0.f, 1.f);
    h  = clipf_(tr[3], 0.f, 1.f);
    best = 0;
    float bi = -1e30f;
    #pragma unroll
    for (int a = 0; a < 3; a++) {
        float aw = c_anchors[s][a][0] / IMGF;
        float ah = c_anchors[s][a][1] / IMGF;
        float v = iou4(0.5f, 0.5f, aw, ah, cx, cy, w, h);
        if (v > bi) { bi = v; best = a; }  // first-max == jnp.argmax
    }
    int H = c_H[s];
    gxi = (int)(cx * (float)H); gxi = min(max(gxi, 0), H - 1);
    gyi = (int)(cy * (float)H); gyi = min(max(gyi, 0), H - 1);
    return 0;
}

// ---- single fused kernel ----
// blocks [0,NBNO): noobj BCE partial per block
// blocks [NBNO,NBLK): positive-cell partials (one wave per (scale,order), inline
//   last-write-wins via same-image later-target ballot)
// last block to finish (atomic counter): final combine -> out[4]
__global__ __launch_bounds__(256) void k_all(const float* __restrict__ p0,
                                             const float* __restrict__ p1,
                                             const float* __restrict__ p2,
                                             const float* __restrict__ targets,
                                             float* __restrict__ noobj_part,   // [NBNO]
                                             float* __restrict__ pos_part,     // [NPOS_BLOCKS*5]
                                             unsigned* __restrict__ done,      // starts at POISON_BASE
                                             float* __restrict__ out) {
    int blk = blockIdx.x;
    int lane = threadIdx.x & 63;
    int wv = threadIdx.x >> 6;

    __shared__ float sm4[4];
    __shared__ float psum[4][5];
    __shared__ unsigned s_old;

    if (blk < NBNO) {
        // ---------- no-object BCE over 256 cells of one scale ----------
        const float* pred; int base, n;
        if (blk < NB0)            { pred = p0; base = 0;         n = N0; }
        else if (blk < NB0 + NB1) { pred = p1; base = NB0;       n = N1; }
        else                      { pred = p2; base = NB0 + NB1; n = N2; }
        int c = (blk - base) * 256 + threadIdx.x;
        float v = 0.f;
        if (c < n) {
            float p = clipf_(sigmoidf_(pred[c * 85 + 4]), 1e-10f, 1.0f);
            v = -log1pf(-p);
        }
        #pragma unroll
        for (int off = 32; off > 0; off >>= 1) v += __shfl_xor(v, off, 64);
        if (lane == 0) sm4[wv] = v;
        __syncthreads();
        if (threadIdx.x == 0)
            noobj_part[blk] = sm4[0] + sm4[1] + sm4[2] + sm4[3];   // thread-0-only store
    } else {
        // ---------- positive cells: one WAVE per (scale, order) ----------
        int bp = blk - NBNO;
        int s = bp / POS_BLOCKS_PER_SCALE;
        int order = (bp % POS_BLOCKS_PER_SCALE) * 4 + wv;   // < 800

        float v_coord = 0.f, v_obj = 0.f, v_noadj = 0.f, v_cls = 0.f, v_np = 0.f;

        int b = order / TT, t = order % TT;
        const float* tr = targets + order * 85;
        float cx, cy, w, h; int best, gxi, gyi;
        if (target_cell(tr, s, cx, cy, w, h, best, gxi, gyi) == 0) {  // wave-uniform
            int H = c_H[s];
            int flat = ((b * 3 + best) * H + gyi) * H + gxi;

            // inline last-write-wins: any LATER valid target in this image on same cell?
            bool lost = false;
            int tp = t + 1 + lane;
            if (tp < TT) {
                const float* tr2 = targets + (b * TT + tp) * 85;
                float cx2, cy2, w2, h2; int best2, gxi2, gyi2;
                if (target_cell(tr2, s, cx2, cy2, w2, h2, best2, gxi2, gyi2) == 0) {
                    int flat2 = ((b * 3 + best2) * H + gyi2) * H + gxi2;
                    lost = (flat2 == flat);
                }
            }
            if (__ballot(lost) == 0ull) {   // this order wins the cell
                const float* pred = (s == 0) ? p0 : (s == 1) ? p1 : p2;
                const float* pc = pred + (long long)flat * 85;

                float px = sigmoidf_(pc[0]);
                float py = sigmoidf_(pc[1]);
                float bx = clipf_((px + (float)gxi) / (float)H, 0.f, 1.f);
                float by = clipf_((py + (float)gyi) / (float)H, 0.f, 1.f);
                float aw = c_anchors[s][best][0], ah = c_anchors[s][best][1];
                float bwv = clipf_(expf(clipf_(pc[2], -10.f, 10.f)) * aw / IMGF, 0.f, 1.f);
                float bhv = clipf_(expf(clipf_(pc[3], -10.f, 10.f)) * ah / IMGF, 0.f, 1.f);
                float iou = iou4(bx, by, bwv, bhv, cx, cy, w, h);

                float p = clipf_(sigmoidf_(pc[4]), 1e-10f, 1.0f);

                // class BCE split across lanes: lane k -> class k (+ class k+64 if k<16)
                float pcv = clipf_(sigmoidf_(pc[5 + lane]), 1e-10f, 1.0f);
                float tc  = clipf_(tr[5 + lane], 0.f, 1.f);
                float cl  = -(tc * logf(pcv) + (1.f - tc) * log1pf(-pcv));
                if (lane < NCLS - 64) {
                    float pcv2 = clipf_(sigmoidf_(pc[5 + 64 + lane]), 1e-10f, 1.0f);
                    float tc2  = clipf_(tr[5 + 64 + lane], 0.f, 1.f);
                    cl += -(tc2 * logf(pcv2) + (1.f - tc2) * log1pf(-pcv2));
                }
                #pragma unroll
                for (int off = 32; off > 0; off >>= 1) cl += __shfl_xor(cl, off, 64);

                v_coord = 1.f - iou;
                v_obj   = -logf(p);
                v_noadj = -log1pf(-p);
                v_cls   = cl;
                v_np    = 1.f;
            }
        }

        if (lane == 0) {
            psum[wv][0] = v_coord; psum[wv][1] = v_obj; psum[wv][2] = v_noadj;
            psum[wv][3] = v_cls;   psum[wv][4] = v_np;
        }
        __syncthreads();
        if (threadIdx.x == 0) {   // thread-0-only store (threadfence release pattern)
            #pragma unroll
            for (int q = 0; q < 5; q++)
                pos_part[bp * 5 + q] = psum[0][q] + psum[1][q] + psum[2][q] + psum[3][q];
        }
    }

    // ---------- completion protocol: last block does the final combine ----------
    __syncthreads();
    if (threadIdx.x == 0) {
        __threadfence();                      // release this block's partial store
        s_old = atomicAdd(done, 1u);          // device-scope
    }
    __syncthreads();
    if (s_old != POISON_BASE + (unsigned)(NBLK - 1)) return;

    __threadfence();                          // acquire: invalidate stale cached partials

    float nsum[3] = {0.f, 0.f, 0.f};
    for (int i = threadIdx.x; i < NBNO; i += 256) {
        float v = noobj_part[i];
        if (i < NB0)            nsum[0] += v;
        else if (i < NB0 + NB1) nsum[1] += v;
        else                    nsum[2] += v;
    }
    float ps[3][5] = {};
    for (int i = threadIdx.x; i < NPOS_BLOCKS; i += 256) {
        int s = i / POS_BLOCKS_PER_SCALE;
        #pragma unroll
        for (int q = 0; q < 5; q++) ps[s][q] += pos_part[i * 5 + q];
    }

    __shared__ float red[18][256];
    #pragma unroll
    for (int s = 0; s < 3; s++) {
        red[s][threadIdx.x] = nsum[s];
        #pragma unroll
        for (int q = 0; q < 5; q++) red[3 + s * 5 + q][threadIdx.x] = ps[s][q];
    }
    __syncthreads();
    for (int off = 128; off > 0; off >>= 1) {
        if (threadIdx.x < off) {
            #pragma unroll
            for (int r = 0; r < 18; r++)
                red[r][threadIdx.x] += red[r][threadIdx.x + off];
        }
        __syncthreads();
    }
    if (threadIdx.x == 0) {
        const float ncell[3] = {(float)N0, (float)N1, (float)N2};
        float coord = 0.f, conf = 0.f, cls = 0.f;
        #pragma unroll
        for (int s = 0; s < 3; s++) {
            float noobjTot = red[s][0];
            float co    = red[3 + s * 5 + 0][0];
            float ob    = red[3 + s * 5 + 1][0];
            float noadj = red[3 + s * 5 + 2][0];
            float cl    = red[3 + s * 5 + 3][0];
            float npos  = red[3 + s * 5 + 4][0];
            float nneg = ncell[s] - npos;
            float dn = fmaxf(npos, 1.f);
            conf += ob / dn + 0.5f * (noobjTot - noadj) / fmaxf(nneg, 1.f);
            if (npos > 0.f) {
                coord += co / dn;
                cls   += cl / fmaxf(npos * (float)NCLS, 1.f);
            }
        }
        out[0] = 5.0f * coord + conf + 1.0f * cls;
        out[1] = coord;
        out[2] = conf;
        out[3] = cls;
    }
}

extern "C" void kernel_launch(void* const* d_in, const int* in_sizes, int n_in,
                              void* d_out, int out_size, void* d_ws, size_t ws_size,
                              hipStream_t stream) {
    const float* p0 = (const float*)d_in[0];
    const float* p1 = (const float*)d_in[1];
    const float* p2 = (const float*)d_in[2];
    const float* tg = (const float*)d_in[3];
    float* out = (float*)d_out;

    char* ws = (char*)d_ws;
    float* noobj_part = (float*)ws;               // NBNO floats (5688 B)
    float* pos_part   = (float*)(ws + 8192);      // NPOS_BLOCKS*5 floats (12000 B)
    unsigned* done    = (unsigned*)(ws + 32768);  // poisoned to 0xAAAAAAAA by harness

    k_all<<<NBLK, 256, 0, stream>>>(p0, p1, p2, tg, noobj_part, pos_part, done, out);
}

// Round 6
// 157.402 us; speedup vs baseline: 1.3220x; 1.3220x over previous
//
#include <hip/hip_runtime.h>
#include <math.h>

// ---------------- problem constants ----------------
#define BB   16      // batch
#define TT   50      // targets per image
#define BT   (BB*TT) // 800
#define NCLS 80
#define IMGF 608.0f

#define H0 76
#define H1 38
#define H2 19
#define N0 277248   // 16*3*76*76
#define N1 69312    // 16*3*38*38
#define N2 17328    // 16*3*19*19
#define NTOT (N0+N1+N2)   // 363888

// noobj: 8 cells per thread -> 8 loads in flight (R5 post-mortem: one load per
// thread was latency-bound at 273 GB/s; Little's law needs more MLP, not BW)
#define CELLS_PER_THREAD 8
#define NOOBJ_BLOCKS ((NTOT + 256*CELLS_PER_THREAD - 1) / (256*CELLS_PER_THREAD))  // 178

#define POS_BLOCKS_PER_SCALE 200               // 4 waves/block * 200 = 800 orders
#define NPOS_BLOCKS (3*POS_BLOCKS_PER_SCALE)   // 600
#define NBLK (NOOBJ_BLOCKS + NPOS_BLOCKS)      // 778

__constant__ float c_anchors[3][3][2] = {
    {{12.f,16.f},{19.f,36.f},{40.f,28.f}},
    {{36.f,75.f},{76.f,55.f},{72.f,146.f}},
    {{142.f,110.f},{192.f,243.f},{459.f,401.f}}};
__constant__ int c_H[3] = {H0, H1, H2};

__device__ __forceinline__ float sigmoidf_(float x) { return 1.0f / (1.0f + expf(-x)); }
__device__ __forceinline__ float clipf_(float x, float lo, float hi) {
    return fminf(fmaxf(x, lo), hi);
}

__device__ __forceinline__ float iou4(float ax, float ay, float aw, float ah,
                                      float bx, float by, float bw, float bh) {
    float ax1 = ax - aw * 0.5f, ay1 = ay - ah * 0.5f;
    float ax2 = ax + aw * 0.5f, ay2 = ay + ah * 0.5f;
    float bx1 = bx - bw * 0.5f, by1 = by - bh * 0.5f;
    float bx2 = bx + bw * 0.5f, by2 = by + bh * 0.5f;
    float iw = fmaxf(fminf(ax2, bx2) - fmaxf(ax1, bx1), 0.f);
    float ih = fmaxf(fminf(ay2, by2) - fmaxf(ay1, by1), 0.f);
    float inter = iw * ih;
    float uni = (ax2 - ax1) * (ay2 - ay1) + (bx2 - bx1) * (by2 - by1) - inter + 1e-7f;
    return inter / uni;
}

// anchor match + cell for one (scale, target row). returns -1 if invalid target
__device__ __forceinline__ int target_cell(const float* tr, int s, float& cx, float& cy,
                                           float& w, float& h, int& best, int& gxi, int& gyi) {
    float t4 = tr[4];
    if (!(t4 > 0.f)) return -1;
    cx = clipf_(tr[0], 0.f, 1.f);
    cy = clipf_(tr[1], 0.f, 1.f);
    w  = clipf_(tr[2], 0.f, 1.f);
    h  = clipf_(tr[3], 0.f, 1.f);
    best = 0;
    float bi = -1e30f;
    #pragma unroll
    for (int a = 0; a < 3; a++) {
        float aw = c_anchors[s][a][0] / IMGF;
        float ah = c_anchors[s][a][1] / IMGF;
        float v = iou4(0.5f, 0.5f, aw, ah, cx, cy, w, h);
        if (v > bi) { bi = v; best = a; }  // first-max == jnp.argmax
    }
    int H = c_H[s];
    gxi = (int)(cx * (float)H); gxi = min(max(gxi, 0), H - 1);
    gyi = (int)(cy * (float)H); gyi = min(max(gyi, 0), H - 1);
    return 0;
}

// ---- main kernel: blocks [0,NOOBJ_BLOCKS) = noobj BCE (8 cells/thread);
//      blocks [NOOBJ_BLOCKS,NBLK) = positive waves. NO completion protocol
//      (R5: 2022 same-address atomics + fences cost ~50us). ----
__global__ __launch_bounds__(256) void k_main(const float* __restrict__ p0,
                                              const float* __restrict__ p1,
                                              const float* __restrict__ p2,
                                              const float* __restrict__ targets,
                                              float* __restrict__ noobj_part,   // [NOOBJ_BLOCKS*3]
                                              float* __restrict__ pos_part) {   // [NPOS_BLOCKS*5]
    int blk = blockIdx.x;
    int lane = threadIdx.x & 63;
    int wv = threadIdx.x >> 6;

    if (blk < NOOBJ_BLOCKS) {
        // ---------- no-object BCE, 8 independent strided loads per thread ----------
        int base = blk * (256 * CELLS_PER_THREAD) + threadIdx.x;
        float vals[CELLS_PER_THREAD];
        #pragma unroll
        for (int k = 0; k < CELLS_PER_THREAD; k++) {
            int g = base + k * 256;
            const float* pred; int c;
            if (g < N0)            { pred = p0; c = g; }
            else if (g < N0 + N1)  { pred = p1; c = g - N0; }
            else                   { pred = p2; c = g - N0 - N1; }
            vals[k] = (g < NTOT) ? pred[(long long)c * 85 + 4] : 0.f;  // all 8 loads issue before use
        }
        float sum[3] = {0.f, 0.f, 0.f};
        #pragma unroll
        for (int k = 0; k < CELLS_PER_THREAD; k++) {
            int g = base + k * 256;
            if (g < NTOT) {
                float p = clipf_(sigmoidf_(vals[k]), 1e-10f, 1.0f);
                float v = -log1pf(-p);
                if (g < N0)           sum[0] += v;
                else if (g < N0 + N1) sum[1] += v;
                else                  sum[2] += v;
            }
        }
        #pragma unroll
        for (int off = 32; off > 0; off >>= 1) {
            sum[0] += __shfl_xor(sum[0], off, 64);
            sum[1] += __shfl_xor(sum[1], off, 64);
            sum[2] += __shfl_xor(sum[2], off, 64);
        }
        __shared__ float sm[4][3];
        if (lane == 0) { sm[wv][0] = sum[0]; sm[wv][1] = sum[1]; sm[wv][2] = sum[2]; }
        __syncthreads();
        if (threadIdx.x < 3)
            noobj_part[blk * 3 + threadIdx.x] =
                sm[0][threadIdx.x] + sm[1][threadIdx.x] + sm[2][threadIdx.x] + sm[3][threadIdx.x];
    } else {
        // ---------- positive cells: one WAVE per (scale, order) ----------
        int bp = blk - NOOBJ_BLOCKS;
        int s = bp / POS_BLOCKS_PER_SCALE;
        int order = (bp % POS_BLOCKS_PER_SCALE) * 4 + wv;   // < 800

        float v_coord = 0.f, v_obj = 0.f, v_noadj = 0.f, v_cls = 0.f, v_np = 0.f;

        int b = order / TT, t = order % TT;
        const float* tr = targets + order * 85;
        float cx, cy, w, h; int best, gxi, gyi;
        if (target_cell(tr, s, cx, cy, w, h, best, gxi, gyi) == 0) {  // wave-uniform
            int H = c_H[s];
            int flat = ((b * 3 + best) * H + gyi) * H + gxi;

            // inline last-write-wins: any LATER valid target in this image on same cell?
            bool lost = false;
            int tp = t + 1 + lane;
            if (tp < TT) {
                const float* tr2 = targets + (b * TT + tp) * 85;
                float cx2, cy2, w2, h2; int best2, gxi2, gyi2;
                if (target_cell(tr2, s, cx2, cy2, w2, h2, best2, gxi2, gyi2) == 0) {
                    int flat2 = ((b * 3 + best2) * H + gyi2) * H + gxi2;
                    lost = (flat2 == flat);
                }
            }
            if (__ballot(lost) == 0ull) {   // this order wins the cell
                const float* pred = (s == 0) ? p0 : (s == 1) ? p1 : p2;
                const float* pc = pred + (long long)flat * 85;

                float px = sigmoidf_(pc[0]);
                float py = sigmoidf_(pc[1]);
                float bx = clipf_((px + (float)gxi) / (float)H, 0.f, 1.f);
                float by = clipf_((py + (float)gyi) / (float)H, 0.f, 1.f);
                float aw = c_anchors[s][best][0], ah = c_anchors[s][best][1];
                float bwv = clipf_(expf(clipf_(pc[2], -10.f, 10.f)) * aw / IMGF, 0.f, 1.f);
                float bhv = clipf_(expf(clipf_(pc[3], -10.f, 10.f)) * ah / IMGF, 0.f, 1.f);
                float iou = iou4(bx, by, bwv, bhv, cx, cy, w, h);

                float p = clipf_(sigmoidf_(pc[4]), 1e-10f, 1.0f);

                // class BCE split across lanes: lane k -> class k (+ class k+64 if k<16)
                float pcv = clipf_(sigmoidf_(pc[5 + lane]), 1e-10f, 1.0f);
                float tc  = clipf_(tr[5 + lane], 0.f, 1.f);
                float cl  = -(tc * logf(pcv) + (1.f - tc) * log1pf(-pcv));
                if (lane < NCLS - 64) {
                    float pcv2 = clipf_(sigmoidf_(pc[5 + 64 + lane]), 1e-10f, 1.0f);
                    float tc2  = clipf_(tr[5 + 64 + lane], 0.f, 1.f);
                    cl += -(tc2 * logf(pcv2) + (1.f - tc2) * log1pf(-pcv2));
                }
                #pragma unroll
                for (int off = 32; off > 0; off >>= 1) cl += __shfl_xor(cl, off, 64);

                v_coord = 1.f - iou;
                v_obj   = -logf(p);
                v_noadj = -log1pf(-p);
                v_cls   = cl;
                v_np    = 1.f;
            }
        }

        __shared__ float psum[4][5];
        if (lane == 0) {
            psum[wv][0] = v_coord; psum[wv][1] = v_obj; psum[wv][2] = v_noadj;
            psum[wv][3] = v_cls;   psum[wv][4] = v_np;
        }
        __syncthreads();
        if (threadIdx.x < 5) {
            pos_part[bp * 5 + threadIdx.x] =
                psum[0][threadIdx.x] + psum[1][threadIdx.x] +
                psum[2][threadIdx.x] + psum[3][threadIdx.x];
        }
    }
}

// ---- kernel D: reduce partials + final combine ----
__global__ __launch_bounds__(256) void k_final(const float* __restrict__ noobj_part,
                                               const float* __restrict__ pos_part,
                                               float* __restrict__ out) {
    float nsum[3] = {0.f, 0.f, 0.f};
    for (int i = threadIdx.x; i < NOOBJ_BLOCKS; i += 256) {
        #pragma unroll
        for (int s = 0; s < 3; s++) nsum[s] += noobj_part[i * 3 + s];
    }
    float ps[3][5] = {};
    for (int i = threadIdx.x; i < NPOS_BLOCKS; i += 256) {
        int s = i / POS_BLOCKS_PER_SCALE;
        #pragma unroll
        for (int q = 0; q < 5; q++) ps[s][q] += pos_part[i * 5 + q];
    }

    __shared__ float red[18][256];
    #pragma unroll
    for (int s = 0; s < 3; s++) {
        red[s][threadIdx.x] = nsum[s];
        #pragma unroll
        for (int q = 0; q < 5; q++) red[3 + s * 5 + q][threadIdx.x] = ps[s][q];
    }
    __syncthreads();
    for (int off = 128; off > 0; off >>= 1) {
        if (threadIdx.x < off) {
            #pragma unroll
            for (int r = 0; r < 18; r++)
                red[r][threadIdx.x] += red[r][threadIdx.x + off];
        }
        __syncthreads();
    }
    if (threadIdx.x == 0) {
        const float ncell[3] = {(float)N0, (float)N1, (float)N2};
        float coord = 0.f, conf = 0.f, cls = 0.f;
        #pragma unroll
        for (int s = 0; s < 3; s++) {
            float noobjTot = red[s][0];
            float co    = red[3 + s * 5 + 0][0];
            float ob    = red[3 + s * 5 + 1][0];
            float noadj = red[3 + s * 5 + 2][0];
            float cl    = red[3 + s * 5 + 3][0];
            float npos  = red[3 + s * 5 + 4][0];
            float nneg = ncell[s] - npos;
            float dn = fmaxf(npos, 1.f);
            conf += ob / dn + 0.5f * (noobjTot - noadj) / fmaxf(nneg, 1.f);
            if (npos > 0.f) {
                coord += co / dn;
                cls   += cl / fmaxf(npos * (float)NCLS, 1.f);
            }
        }
        out[0] = 5.0f * coord + conf + 1.0f * cls;
        out[1] = coord;
        out[2] = conf;
        out[3] = cls;
    }
}

extern "C" void kernel_launch(void* const* d_in, const int* in_sizes, int n_in,
                              void* d_out, int out_size, void* d_ws, size_t ws_size,
                              hipStream_t stream) {
    const float* p0 = (const float*)d_in[0];
    const float* p1 = (const float*)d_in[1];
    const float* p2 = (const float*)d_in[2];
    const float* tg = (const float*)d_in[3];
    float* out = (float*)d_out;

    char* ws = (char*)d_ws;
    float* noobj_part = (float*)ws;              // NOOBJ_BLOCKS*3 floats (2136 B)
    float* pos_part   = (float*)(ws + 4096);     // NPOS_BLOCKS*5 floats (12000 B)

    k_main<<<NBLK, 256, 0, stream>>>(p0, p1, p2, tg, noobj_part, pos_part);
    k_final<<<1, 256, 0, stream>>>(noobj_part, pos_part, out);
}